// Round 8
// baseline (411.631 us; speedup 1.0000x reference)
//
#include <hip/hip_runtime.h>
#include <hip/hip_bf16.h>

// ---------------------------------------------------------------------------
// MultiHeadAttention: B=4, T=1024, E=768, D=768, H=8, per-head full-width proj
// QKV & S GEMMs: 256x256-tile 8-wave 4-phase pipelined kernel (gemm256):
//   sched_barrier-pinned phases, barrier-protected staging, counted vmcnt(4),
//   T2 XOR swizzle (0 conflicts), T5 setprio, T1 XCD swizzle.
// PV / out-proj / fallback: proven 128x128 kernel (R6/R7).
// Softmax fused into S epilogue (exp + row partial sums); PV scales by 1/den.
// ---------------------------------------------------------------------------

typedef __bf16 bf16x8 __attribute__((ext_vector_type(8)));
typedef float  f32x4  __attribute__((ext_vector_type(4)));
typedef short  s16x4  __attribute__((ext_vector_type(4)));

#define AS1 __attribute__((address_space(1)))
#define AS3 __attribute__((address_space(3)))

__device__ inline void gload_lds16(const void* g, void* l) {
  __builtin_amdgcn_global_load_lds((AS1 const void*)g, (AS3 void*)l, 16, 0, 0);
}

__device__ inline unsigned short f2bf(float f) {  // RNE f32 -> bf16 bits
  union { float f; unsigned u; } c; c.f = f;
  unsigned r = c.u + 0x7FFF + ((c.u >> 16) & 1);
  return (unsigned short)(r >> 16);
}
__device__ inline float bf2f(unsigned short u) {
  return __uint_as_float(((unsigned)u) << 16);
}

// XCD-aware bijective remap (T1); valid when total blocks % 8 == 0
__device__ inline void swizzle_bid(int& bx, int& by, int& bz) {
  const int gx = gridDim.x, gy = gridDim.y, gz = gridDim.z;
  const int n = gx * gy * gz;
  if ((n & 7) == 0) {
    int lin = (blockIdx.z * gy + blockIdx.y) * gx + blockIdx.x;
    lin = (lin & 7) * (n >> 3) + (lin >> 3);
    bz = lin / (gx * gy);
    const int rem = lin - bz * gx * gy;
    by = rem / gx;
    bx = rem - by * gx;
  } else {
    bx = blockIdx.x; by = blockIdx.y; bz = blockIdx.z;
  }
}

// stage 2 chunks (2 x 64 rows) of a 256x64 bf16 tile; pre-swizzled source
// (unit su = u ^ (row&7)) so linear gload_lds dest yields T2-swizzled LDS.
__device__ __forceinline__ void stage2_256(const unsigned short* __restrict__ G,
                                           int ld, int kbase,
                                           unsigned short* lbase,
                                           int tid, int wave, int cc0) {
  const int sr = tid >> 3;
  const int su = (tid & 7) ^ ((tid >> 3) & 7);
#pragma unroll
  for (int cc = cc0; cc < cc0 + 2; ++cc)
    gload_lds16(G + (size_t)(cc * 64 + sr) * ld + kbase + su * 8,
                lbase + (cc * 64 + wave * 8) * 64);
}

#define LGK0_PIN() do { \
    asm volatile("s_waitcnt lgkmcnt(0)" ::: "memory"); \
    __builtin_amdgcn_sched_barrier(0); } while (0)

// ---------------------------------------------------------------------------
// gemm256: C = scale * A * Bt^T; A:[M,lda], Bt:[N,ldb] bf16.
// Grid (N/256, M/256, Z), 512 thr (8 waves: 2M x 4N), wave out 128x64.
// LDS 128 KiB dynamic: buf b at b*32768 shorts {A[256][64], B[256][64]}.
// 4 phases/K-tile: ph0 {B kk0 + A mh0 kk0}, ph1 {A mh1 kk0},
// ph2 {B kk1 + A mh0 kk1}, ph3 {A mh1 kk1}.
// Stage: A(t+1)->other buf at ph0/ph1 (its old content read last tile);
// B(t+2)->this buf's B at ph3 (one barrier after B's last read at ph2).
// Fence: vmcnt(4) at ph3 (drains A(t+1)+B(t+1), keeps B(t+2) in flight).
// MODE 1: QKV (z<16 normal bf16 +bias; z>=16 write vT[b][z-16][n][t]).
// MODE 2: S (e=exp(v*scale) bf16 + rowsum[(z*4+ntile)*1024+m] partials).
// ---------------------------------------------------------------------------
template<int MODE>
__global__ __launch_bounds__(512, 2)
void gemm256_kernel(const unsigned short* __restrict__ A,
                    const unsigned short* __restrict__ Bt,
                    void* __restrict__ Cout,
                    const float* __restrict__ bias,
                    int K, int lda, int ldb,
                    long long aZ, long long bZ,
                    long long cZhi, long long cZlo, int zShift,
                    long long cRowHi, int rowShift, int ldc,
                    long long biasZ, float scale,
                    unsigned short* __restrict__ vtOut,
                    float* __restrict__ rowsumOut)
{
  extern __shared__ unsigned short sm[];   // 65536 shorts = 128 KiB

  int ntile, mtile, z;
  swizzle_bid(ntile, mtile, z);

  const int tid  = threadIdx.x;
  const int wave = tid >> 6;
  const int lane = tid & 63;
  const int wm = wave >> 2, wn = wave & 3;

  const unsigned short* Ab = A  + (size_t)z * aZ + (size_t)mtile * 256 * lda;
  const unsigned short* Bb = Bt + (size_t)z * bZ + (size_t)ntile * 256 * ldb;

  const int rsel  = lane & 15;
  const int usel  = lane & 7;
  const int ubase = lane >> 4;
  const int koff0 = ((ubase) ^ usel) * 8;
  const int koff1 = ((4 | ubase) ^ usel) * 8;

  f32x4 acc[8][4] = {};

  const int nkt = K >> 6;
  // prologue: A(0),B(0)->buf0; B(1)->buf1.B; drain A0,B0, keep B1 in flight
  stage2_256(Ab, lda, 0, sm, tid, wave, 0);
  stage2_256(Ab, lda, 0, sm, tid, wave, 2);
  stage2_256(Bb, ldb, 0, sm + 16384, tid, wave, 0);
  stage2_256(Bb, ldb, 0, sm + 16384, tid, wave, 2);
  if (nkt > 1) {
    stage2_256(Bb, ldb, 64, sm + 32768 + 16384, tid, wave, 0);
    stage2_256(Bb, ldb, 64, sm + 32768 + 16384, tid, wave, 2);
    asm volatile("s_waitcnt vmcnt(4)" ::: "memory");
  } else {
    asm volatile("s_waitcnt vmcnt(0)" ::: "memory");
  }
  __builtin_amdgcn_sched_barrier(0);
  __builtin_amdgcn_s_barrier();

  for (int t = 0; t < nkt; ++t) {
    const unsigned short* Ac = sm + (t & 1) * 32768;
    const unsigned short* Bc = Ac + 16384;
    unsigned short* An = sm + ((t + 1) & 1) * 32768;            // A(t+1) dest
    unsigned short* Bn = sm + (t & 1) * 32768 + 16384;          // B(t+2) dest
    const int kb1 = (t + 1) * 64, kb2 = (t + 2) * 64;
    bf16x8 a[4], b0[4], b1[4];

    // ---------- ph0: B kk0 + A mh0 kk0 ; stage A(t+1) c01 ----------
#pragma unroll
    for (int f = 0; f < 4; ++f) {
      b0[f] = *(const bf16x8*)&Bc[(wn * 64 + f * 16 + rsel) * 64 + koff0];
      a[f]  = *(const bf16x8*)&Ac[(wm * 128 + f * 16 + rsel) * 64 + koff0];
    }
    __builtin_amdgcn_sched_barrier(0);
    if (t + 1 < nkt) stage2_256(Ab, lda, kb1, An, tid, wave, 0);
    __builtin_amdgcn_sched_barrier(0);
    __builtin_amdgcn_s_barrier();
    LGK0_PIN();
    __builtin_amdgcn_s_setprio(1);
#pragma unroll
    for (int fm = 0; fm < 4; ++fm)
#pragma unroll
      for (int fn = 0; fn < 4; ++fn)
        acc[fm][fn] = __builtin_amdgcn_mfma_f32_16x16x32_bf16(a[fm], b0[fn], acc[fm][fn], 0, 0, 0);
    __builtin_amdgcn_s_setprio(0);
    __builtin_amdgcn_sched_barrier(0);
    __builtin_amdgcn_s_barrier();

    // ---------- ph1: A mh1 kk0 ; stage A(t+1) c23 ----------
#pragma unroll
    for (int f = 0; f < 4; ++f)
      a[f] = *(const bf16x8*)&Ac[(wm * 128 + 64 + f * 16 + rsel) * 64 + koff0];
    __builtin_amdgcn_sched_barrier(0);
    if (t + 1 < nkt) stage2_256(Ab, lda, kb1, An, tid, wave, 2);
    __builtin_amdgcn_sched_barrier(0);
    __builtin_amdgcn_s_barrier();
    LGK0_PIN();
    __builtin_amdgcn_s_setprio(1);
#pragma unroll
    for (int fm = 0; fm < 4; ++fm)
#pragma unroll
      for (int fn = 0; fn < 4; ++fn)
        acc[4 + fm][fn] = __builtin_amdgcn_mfma_f32_16x16x32_bf16(a[fm], b0[fn], acc[4 + fm][fn], 0, 0, 0);
    __builtin_amdgcn_s_setprio(0);
    __builtin_amdgcn_sched_barrier(0);
    __builtin_amdgcn_s_barrier();

    // ---------- ph2: B kk1 + A mh0 kk1 ----------
#pragma unroll
    for (int f = 0; f < 4; ++f) {
      b1[f] = *(const bf16x8*)&Bc[(wn * 64 + f * 16 + rsel) * 64 + koff1];
      a[f]  = *(const bf16x8*)&Ac[(wm * 128 + f * 16 + rsel) * 64 + koff1];
    }
    __builtin_amdgcn_sched_barrier(0);
    __builtin_amdgcn_s_barrier();
    LGK0_PIN();
    __builtin_amdgcn_s_setprio(1);
#pragma unroll
    for (int fm = 0; fm < 4; ++fm)
#pragma unroll
      for (int fn = 0; fn < 4; ++fn)
        acc[fm][fn] = __builtin_amdgcn_mfma_f32_16x16x32_bf16(a[fm], b1[fn], acc[fm][fn], 0, 0, 0);
    __builtin_amdgcn_s_setprio(0);
    __builtin_amdgcn_sched_barrier(0);
    __builtin_amdgcn_s_barrier();

    // ---------- ph3: A mh1 kk1 ; stage B(t+2) ; counted fence ----------
#pragma unroll
    for (int f = 0; f < 4; ++f)
      a[f] = *(const bf16x8*)&Ac[(wm * 128 + 64 + f * 16 + rsel) * 64 + koff1];
    __builtin_amdgcn_sched_barrier(0);
    if (t + 2 < nkt) {
      stage2_256(Bb, ldb, kb2, Bn, tid, wave, 0);
      stage2_256(Bb, ldb, kb2, Bn, tid, wave, 2);
      asm volatile("s_waitcnt vmcnt(4)" ::: "memory");
    } else {
      asm volatile("s_waitcnt vmcnt(0)" ::: "memory");
    }
    __builtin_amdgcn_sched_barrier(0);
    __builtin_amdgcn_s_barrier();
    LGK0_PIN();
    __builtin_amdgcn_s_setprio(1);
#pragma unroll
    for (int fm = 0; fm < 4; ++fm)
#pragma unroll
      for (int fn = 0; fn < 4; ++fn)
        acc[4 + fm][fn] = __builtin_amdgcn_mfma_f32_16x16x32_bf16(a[fm], b1[fn], acc[4 + fm][fn], 0, 0, 0);
    __builtin_amdgcn_s_setprio(0);
    __builtin_amdgcn_sched_barrier(0);
    __builtin_amdgcn_s_barrier();
  }

  // ---------------- epilogues (C/D layout: col=lane&15, row=(lane>>4)*4+j) --
  if (MODE == 1 && z >= 16) {
    const long long hoff = (long long)(z - 16) * 786432LL;   // D*T
#pragma unroll
    for (int fm = 0; fm < 8; ++fm) {
#pragma unroll
      for (int fn = 0; fn < 4; ++fn) {
        const int n  = ntile * 256 + wn * 64 + fn * 16 + (lane & 15);
        const int m0 = mtile * 256 + wm * 128 + fm * 16 + (lane >> 4) * 4;
        const int b  = m0 >> 10, t0 = m0 & 1023;
        const float bb = bias ? bias[(size_t)z * biasZ + n] : 0.f;
        s16x4 w;
#pragma unroll
        for (int j = 0; j < 4; ++j)
          w[j] = (short)f2bf(acc[fm][fn][j] * scale + bb);
        *(s16x4*)&vtOut[(size_t)b * 6291456 + hoff + (size_t)n * 1024 + t0] = w;
      }
    }
    return;
  }

  const long long zoff = (long long)(z >> zShift) * cZhi
                       + (long long)(z & ((1 << zShift) - 1)) * cZlo;

  if (MODE == 2) {
    __syncthreads();
    float* redsum = (float*)sm;   // [256][4]
#pragma unroll
    for (int fm = 0; fm < 8; ++fm) {
#pragma unroll
      for (int j = 0; j < 4; ++j) {
        const int rl = wm * 128 + fm * 16 + (lane >> 4) * 4 + j;
        const int m  = mtile * 256 + rl;
        const long long rowoff = (long long)(m >> rowShift) * cRowHi
                               + (long long)(m & ((1 << rowShift) - 1)) * ldc;
        float part = 0.f;
#pragma unroll
        for (int fn = 0; fn < 4; ++fn) {
          const int n = ntile * 256 + wn * 64 + fn * 16 + (lane & 15);
          const float e = __expf(acc[fm][fn][j] * scale);
          part += e;
          ((unsigned short*)Cout)[zoff + rowoff + n] = f2bf(e);
        }
#pragma unroll
        for (int o = 1; o < 16; o <<= 1) part += __shfl_xor(part, o);
        if ((lane & 15) == 0) redsum[rl * 4 + wn] = part;
      }
    }
    __syncthreads();
    if (tid < 256) {
      rowsumOut[((long long)z * 4 + ntile) * 1024 + mtile * 256 + tid] =
          redsum[tid * 4] + redsum[tid * 4 + 1] + redsum[tid * 4 + 2] + redsum[tid * 4 + 3];
    }
    return;
  }

  // MODE 1, z<16: normal bf16 store + bias
#pragma unroll
  for (int fm = 0; fm < 8; ++fm) {
#pragma unroll
    for (int j = 0; j < 4; ++j) {
      const int m = mtile * 256 + wm * 128 + fm * 16 + (lane >> 4) * 4 + j;
      const long long rowoff = (long long)(m >> rowShift) * cRowHi
                             + (long long)(m & ((1 << rowShift) - 1)) * ldc;
#pragma unroll
      for (int fn = 0; fn < 4; ++fn) {
        const int n = ntile * 256 + wn * 64 + fn * 16 + (lane & 15);
        float v = acc[fm][fn][j] * scale;
        if (bias) v += bias[(size_t)z * biasZ + n];
        ((unsigned short*)Cout)[zoff + rowoff + n] = f2bf(v);
      }
    }
  }
}

// ---------------------------------------------------------------------------
// 128x128 GEMM (proven R6/R7) — PV, out-proj, and fallback paths
// ---------------------------------------------------------------------------
template<bool OUT_F32>
__global__ __launch_bounds__(256, 2)
void gemm_bt_kernel(const unsigned short* __restrict__ A,
                    const unsigned short* __restrict__ Bt,
                    void* __restrict__ Cout,
                    const float* __restrict__ bias,
                    int K, int lda, int ldb,
                    long long aZ, long long bZ,
                    long long cZhi, long long cZlo, int zShift,
                    long long cRowHi, int rowShift, int ldc,
                    long long biasZ, float scale,
                    unsigned short* __restrict__ vtOut,
                    float* __restrict__ rowsumOut,
                    const float* __restrict__ rowScale)
{
  __shared__ unsigned short As[128 * 64];
  __shared__ unsigned short Bs[128 * 64];

  int ntile, mtile, z;
  swizzle_bid(ntile, mtile, z);

  const int tid  = threadIdx.x;
  const int wave = tid >> 6;
  const int lane = tid & 63;
  const int wm = wave >> 1, wn = wave & 1;

  const unsigned short* Ab = A  + (size_t)z * aZ + (size_t)mtile * 128 * lda;
  const unsigned short* Bb = Bt + (size_t)z * bZ + (size_t)ntile * 128 * ldb;

  const int rlane = lane >> 3;
  const int su    = ((lane & 7) ^ rlane) * 8;

  const int rsel  = lane & 15;
  const int usel  = lane & 7;
  const int ubase = lane >> 4;
  const int koff0 = ((ubase) ^ usel) * 8;
  const int koff1 = ((4 | ubase) ^ usel) * 8;

  f32x4 acc[4][4] = {};

  const int nkt = K >> 6;
  for (int kt = 0; kt < nkt; ++kt) {
    const int kbase = kt * 64;
    __syncthreads();
#pragma unroll
    for (int i = 0; i < 4; ++i) {
      const int r = wave * 32 + i * 8;
      gload_lds16(Ab + (size_t)(r + rlane) * lda + kbase + su, &As[r * 64]);
      gload_lds16(Bb + (size_t)(r + rlane) * ldb + kbase + su, &Bs[r * 64]);
    }
    __syncthreads();
#pragma unroll
    for (int kk = 0; kk < 2; ++kk) {
      const int koff = kk ? koff1 : koff0;
      bf16x8 af[4], bfr[4];
#pragma unroll
      for (int f = 0; f < 4; ++f) {
        af[f]  = *(const bf16x8*)&As[(wm * 64 + f * 16 + rsel) * 64 + koff];
        bfr[f] = *(const bf16x8*)&Bs[(wn * 64 + f * 16 + rsel) * 64 + koff];
      }
#pragma unroll
      for (int fm = 0; fm < 4; ++fm)
#pragma unroll
        for (int fn = 0; fn < 4; ++fn)
          acc[fm][fn] = __builtin_amdgcn_mfma_f32_16x16x32_bf16(af[fm], bfr[fn], acc[fm][fn], 0, 0, 0);
    }
  }

  if (vtOut && z >= 16) {
    const long long hoff = (long long)(z - 16) * 786432LL;
#pragma unroll
    for (int fm = 0; fm < 4; ++fm) {
#pragma unroll
      for (int fn = 0; fn < 4; ++fn) {
        const int n  = ntile * 128 + wn * 64 + fn * 16 + (lane & 15);
        const int m0 = mtile * 128 + wm * 64 + fm * 16 + (lane >> 4) * 4;
        const int b  = m0 >> 10, t0 = m0 & 1023;
        const float bb = bias ? bias[(size_t)z * biasZ + n] : 0.f;
        s16x4 w;
#pragma unroll
        for (int j = 0; j < 4; ++j)
          w[j] = (short)f2bf(acc[fm][fn][j] * scale + bb);
        *(s16x4*)&vtOut[(size_t)b * 6291456 + hoff + (size_t)n * 1024 + t0] = w;
      }
    }
    return;
  }

  const long long zoff = (long long)(z >> zShift) * cZhi
                       + (long long)(z & ((1 << zShift) - 1)) * cZlo;

  if (rowsumOut) {
    __syncthreads();
    float* redsum = (float*)As;
#pragma unroll
    for (int fm = 0; fm < 4; ++fm) {
#pragma unroll
      for (int j = 0; j < 4; ++j) {
        const int m = mtile * 128 + wm * 64 + fm * 16 + (lane >> 4) * 4 + j;
        const long long rowoff = (long long)(m >> rowShift) * cRowHi
                               + (long long)(m & ((1 << rowShift) - 1)) * ldc;
        float part = 0.f;
#pragma unroll
        for (int fn = 0; fn < 4; ++fn) {
          const int n = ntile * 128 + wn * 64 + fn * 16 + (lane & 15);
          const float e = __expf(acc[fm][fn][j] * scale);
          part += e;
          ((unsigned short*)Cout)[zoff + rowoff + n] = f2bf(e);
        }
#pragma unroll
        for (int o = 1; o < 16; o <<= 1) part += __shfl_xor(part, o);
        if ((lane & 15) == 0)
          redsum[(wm * 64 + fm * 16 + (lane >> 4) * 4 + j) * 2 + wn] = part;
      }
    }
    __syncthreads();
    if (tid < 128) {
      const int m = mtile * 128 + tid;
      rowsumOut[((long long)z * 8 + ntile) * 1024 + m] =
          redsum[tid * 2 + 0] + redsum[tid * 2 + 1];
    }
    return;
  }

#pragma unroll
  for (int fm = 0; fm < 4; ++fm) {
#pragma unroll
    for (int j = 0; j < 4; ++j) {
      const int m = mtile * 128 + wm * 64 + fm * 16 + (lane >> 4) * 4 + j;
      const long long rowoff = (long long)(m >> rowShift) * cRowHi
                             + (long long)(m & ((1 << rowShift) - 1)) * ldc;
      const float rsc = rowScale ? rowScale[(size_t)z * 1024 + (m & 1023)] : 1.0f;
#pragma unroll
      for (int fn = 0; fn < 4; ++fn) {
        const int n = ntile * 128 + wn * 64 + fn * 16 + (lane & 15);
        float v = acc[fm][fn][j] * scale;
        if (bias) v += bias[(size_t)z * biasZ + n];
        v *= rsc;
        const long long cidx = zoff + rowoff + n;
        if (OUT_F32) ((float*)Cout)[cidx] = v;
        else ((unsigned short*)Cout)[cidx] = f2bf(v);
      }
    }
  }
}

// merged weight prep: z<24 -> wq/wk/wv head (z&7) -> wqkvT[z]; z>=24 -> woT
__global__ void prep_weights_kernel(const float* __restrict__ wq,
                                    const float* __restrict__ wk,
                                    const float* __restrict__ wv,
                                    const float* __restrict__ wo,
                                    unsigned short* __restrict__ wqkvT,
                                    unsigned short* __restrict__ woT)
{
  __shared__ float tile[32][33];
  const int z = blockIdx.z;
  const float* in;
  unsigned short* outp;
  int outLD;
  if (z < 24) {
    const float* base = (z < 8) ? wq : (z < 16) ? wk : wv;
    in   = base + (size_t)(z & 7) * 589824;
    outp = wqkvT + (size_t)z * 589824;
    outLD = 768;
  } else {
    in   = wo + (size_t)(z - 24) * 589824;
    outp = woT + (size_t)(z - 24) * 768;
    outLD = 6144;
  }
  const int c0 = blockIdx.x * 32, r0 = blockIdx.y * 32;
  const int tx = threadIdx.x, ty = threadIdx.y;
#pragma unroll
  for (int i = ty; i < 32; i += 8)
    tile[i][tx] = in[(size_t)(r0 + i) * 768 + c0 + tx];
  __syncthreads();
#pragma unroll
  for (int i = ty; i < 32; i += 8)
    outp[(size_t)(c0 + i) * outLD + r0 + tx] = f2bf(tile[tx][i]);
}

// fp32 [Z][R][C] -> bf16 [Z][C][R] (fallback path)
__global__ void transpose_conv_kernel(const float* __restrict__ in,
                                      unsigned short* __restrict__ out,
                                      int R, int C)
{
  __shared__ float tile[32][33];
  const size_t zo = (size_t)blockIdx.z * R * C;
  const int c0 = blockIdx.x * 32, r0 = blockIdx.y * 32;
  const int tx = threadIdx.x, ty = threadIdx.y;
#pragma unroll
  for (int i = ty; i < 32; i += 8)
    tile[i][tx] = in[zo + (size_t)(r0 + i) * C + c0 + tx];
  __syncthreads();
#pragma unroll
  for (int i = ty; i < 32; i += 8)
    out[zo + (size_t)(c0 + i) * R + r0 + tx] = f2bf(tile[tx][i]);
}

// bf16 [Z][R][C] -> bf16 [Z][C][R] (fallback path)
__global__ void transpose_bf16_kernel(const unsigned short* __restrict__ in,
                                      unsigned short* __restrict__ out,
                                      int R, int C)
{
  __shared__ unsigned short tile[32][33];
  const size_t zo = (size_t)blockIdx.z * R * C;
  const int c0 = blockIdx.x * 32, r0 = blockIdx.y * 32;
  const int tx = threadIdx.x, ty = threadIdx.y;
#pragma unroll
  for (int i = ty; i < 32; i += 8)
    tile[i][tx] = in[zo + (size_t)(r0 + i) * C + c0 + tx];
  __syncthreads();
#pragma unroll
  for (int i = ty; i < 32; i += 8)
    out[zo + (size_t)(c0 + i) * R + r0 + tx] = tile[tx][i];
}

__global__ void convert_f32_bf16_kernel(const float* __restrict__ in,
                                        unsigned short* __restrict__ out, int n4)
{
  const int i = blockIdx.x * blockDim.x + threadIdx.x;
  if (i < n4) {
    const float4 f = ((const float4*)in)[i];
    s16x4 o;
    o[0] = (short)f2bf(f.x); o[1] = (short)f2bf(f.y);
    o[2] = (short)f2bf(f.z); o[3] = (short)f2bf(f.w);
    ((s16x4*)out)[i] = o;
  }
}

__global__ void bosum_kernel(const float* __restrict__ bo, float* __restrict__ bos)
{
  const int e = blockIdx.x * blockDim.x + threadIdx.x;
  if (e < 768) {
    float s = 0.f;
#pragma unroll
    for (int h = 0; h < 8; ++h) s += bo[h * 768 + e];
    bos[e] = s;
  }
}

__global__ void bconcat_kernel(const float* __restrict__ bq,
                               const float* __restrict__ bk,
                               const float* __restrict__ bv,
                               float* __restrict__ bqkv)
{
  const int i = blockIdx.x * blockDim.x + threadIdx.x;
  if (i < 24 * 768) {
    const int z = i / 768, d = i - z * 768;
    const float* src = (z < 8) ? bq : (z < 16) ? bk : bv;
    bqkv[i] = src[(z & 7) * 768 + d];
  }
}

// invden[z*1024+t] = 1 / sum_{nt<NT} rowsum[(z*NT+nt)*1024 + t]
__global__ void invden_kernel(const float* __restrict__ rowsum,
                              float* __restrict__ invden, int NT)
{
  const int i = blockIdx.x * blockDim.x + threadIdx.x;
  if (i < 32 * 1024) {
    const int z = i >> 10, t = i & 1023;
    const float* p = rowsum + (size_t)z * NT * 1024 + t;
    float s = 0.f;
    for (int nt = 0; nt < NT; ++nt) s += p[nt * 1024];
    invden[i] = 1.0f / s;
  }
}

__global__ void reduce4_kernel(const float* __restrict__ partials,
                               const float* __restrict__ bos,
                               float* __restrict__ out, int n4)
{
  const int i = blockIdx.x * blockDim.x + threadIdx.x;
  if (i < n4) {
    const long long stride4 = 4096LL * 768 / 4;
    float4 a = ((const float4*)partials)[i];
    float4 b = ((const float4*)partials)[i + stride4];
    float4 c = ((const float4*)partials)[i + 2 * stride4];
    float4 d = ((const float4*)partials)[i + 3 * stride4];
    const int col = (i * 4) % 768;
    const float4 b4 = *(const float4*)&bos[col];
    float4 r;
    r.x = a.x + b.x + c.x + d.x + b4.x;
    r.y = a.y + b.y + c.y + d.y + b4.y;
    r.z = a.z + b.z + c.z + d.z + b4.z;
    r.w = a.w + b.w + c.w + d.w + b4.w;
    ((float4*)out)[i] = r;
  }
}

// in-place row softmax (fallback path only)
__global__ __launch_bounds__(256)
void softmax_kernel(unsigned short* __restrict__ S)
{
  const size_t row = blockIdx.x;
  unsigned short* p = S + row * 1024;
  const int t = threadIdx.x;

  s16x4 raw = *((const s16x4*)p + t);
  float v[4];
#pragma unroll
  for (int j = 0; j < 4; ++j) v[j] = bf2f((unsigned short)raw[j]);

  float mx = fmaxf(fmaxf(v[0], v[1]), fmaxf(v[2], v[3]));
#pragma unroll
  for (int o = 1; o < 64; o <<= 1) mx = fmaxf(mx, __shfl_xor(mx, o));

  __shared__ float red[8];
  if ((t & 63) == 0) red[t >> 6] = mx;
  __syncthreads();
  mx = fmaxf(fmaxf(red[0], red[1]), fmaxf(red[2], red[3]));

  float e[4], s = 0.f;
#pragma unroll
  for (int j = 0; j < 4; ++j) { e[j] = __expf(v[j] - mx); s += e[j]; }
#pragma unroll
  for (int o = 1; o < 64; o <<= 1) s += __shfl_xor(s, o);
  if ((t & 63) == 0) red[4 + (t >> 6)] = s;
  __syncthreads();
  s = red[4] + red[5] + red[6] + red[7];
  const float inv = 1.0f / s;

  s16x4 outv;
#pragma unroll
  for (int j = 0; j < 4; ++j) outv[j] = (short)f2bf(e[j] * inv);
  *((s16x4*)p + t) = outv;
}

// ---------------------------------------------------------------------------
extern "C" void kernel_launch(void* const* d_in, const int* in_sizes, int n_in,
                              void* d_out, int out_size, void* d_ws, size_t ws_size,
                              hipStream_t stream)
{
  (void)in_sizes; (void)n_in; (void)out_size;
  constexpr int Bb = 4, T = 1024, E = 768, D = 768, H = 8;
  constexpr int HD = H * D;
  constexpr long long TD = (long long)T * D;
  constexpr long long TT = (long long)T * T;
  constexpr long long DE = (long long)D * E;
  constexpr long long DT = (long long)D * T;
  constexpr long long BHTD = (long long)Bb * H * T * D;
  constexpr long long HTD = (long long)H * TD;
  constexpr float SCALE = 0.03608439182435161f;   // 1/sqrt(E)

  const float* x  = (const float*)d_in[0];
  const float* wq = (const float*)d_in[1];
  const float* bq = (const float*)d_in[2];
  const float* wk = (const float*)d_in[3];
  const float* bk = (const float*)d_in[4];
  const float* wv = (const float*)d_in[5];
  const float* bv = (const float*)d_in[6];
  const float* wo = (const float*)d_in[7];
  const float* bo = (const float*)d_in[8];
  float* out = (float*)d_out;

  unsigned char* wsb = (unsigned char*)d_ws;
  const dim3 tb32(32, 8);

  bool use256 = true;
  if (hipFuncSetAttribute(reinterpret_cast<const void*>(gemm256_kernel<1>),
                          hipFuncAttributeMaxDynamicSharedMemorySize, 131072)
      != hipSuccess) use256 = false;
  if (hipFuncSetAttribute(reinterpret_cast<const void*>(gemm256_kernel<2>),
                          hipFuncAttributeMaxDynamicSharedMemorySize, 131072)
      != hipSuccess) use256 = false;

  // ---- ALL32 tier peak footprint: 245,443,584 B ----
  if (ws_size >= 245443584ULL + 4096ULL) {
    unsigned short* woT   = (unsigned short*)(wsb + 0);
    float*          bos   = (float*)(wsb + 9437184);
    float*          bqkv  = (float*)(wsb + 9440256);
    unsigned short* vT    = (unsigned short*)(wsb + 9513984);
    unsigned short* qkv   = (unsigned short*)(wsb + 59845632);
    unsigned short* q     = qkv;
    unsigned short* k     = qkv + BHTD;
    unsigned short* xb    = (unsigned short*)(wsb + 210840576);
    unsigned short* wqkvT = (unsigned short*)(wsb + 217132032);
    unsigned short* S     = qkv + 2 * BHTD;
    float*          part  = (float*)k;
    unsigned short* z2    = q;
    float*          rowsum = (float*)(wsb + 227617792);
    float*          invden = (float*)(wsb + 228666368);

    convert_f32_bf16_kernel<<<3072, 256, 0, stream>>>(x, xb, Bb * T * E / 4);
    prep_weights_kernel<<<dim3(24, 24, 32), tb32, 0, stream>>>(
        wq, wk, wv, wo, wqkvT, woT);
    bosum_kernel<<<3, 256, 0, stream>>>(bo, bos);
    bconcat_kernel<<<72, 256, 0, stream>>>(bq, bk, bv, bqkv);

    if (use256) {
      // fused QKV (z = proj*8 + h); V (z>=16) writes vT directly
      gemm256_kernel<1><<<dim3(3, 16, 24), 512, 131072, stream>>>(
          xb, wqkvT, qkv, bqkv, E, E, E,
          0LL, DE, BHTD, TD, 3, HTD, 10, D, 768LL, 1.0f, vT, nullptr);
      // E = exp(scale*qk^T) + row partial sums (NT=4)
      gemm256_kernel<2><<<dim3(4, 4, 32), 512, 131072, stream>>>(
          q, k, S, nullptr, D, D, D,
          TD, TD, TT, 0LL, 0, 0LL, 30, T, 0LL, SCALE, nullptr, rowsum);
      invden_kernel<<<128, 256, 0, stream>>>(rowsum, invden, 4);
    } else {
      gemm_bt_kernel<false><<<dim3(6, 32, 24), 256, 0, stream>>>(
          xb, wqkvT, qkv, bqkv, E, E, E,
          0LL, DE, BHTD, TD, 3, HTD, 10, D, 768LL, 1.0f, vT, nullptr, nullptr);
      gemm_bt_kernel<false><<<dim3(8, 8, 32), 256, 0, stream>>>(
          q, k, S, nullptr, D, D, D,
          TD, TD, TT, 0LL, 0, 0LL, 30, T, 0LL, SCALE, nullptr, rowsum, nullptr);
      invden_kernel<<<128, 256, 0, stream>>>(rowsum, invden, 8);
    }

    // z2[b,t,h*D+n] = (E v) * invden
    gemm_bt_kernel<false><<<dim3(6, 8, 32), 256, 0, stream>>>(
        S, vT, z2, nullptr, T, T, T,
        TT, DT, (long long)T * HD, (long long)D, 3, 0LL, 30, HD, 0LL, 1.0f,
        nullptr, nullptr, invden);

    // out-proj split-K=4
    gemm_bt_kernel<true><<<dim3(6, 32, 4), 256, 0, stream>>>(
        z2, woT, part, nullptr, 1536, HD, HD,
        1536LL, 1536LL, 3145728LL, 0LL, 0, 0LL, 30, E, 0LL, 1.0f,
        nullptr, nullptr, nullptr);
    reduce4_kernel<<<3072, 256, 0, stream>>>(part, bos, out, 4096 * 768 / 4);
    return;
  }

  // ---------------- fallback: proven chunked path ----------------
  const size_t FIXED = 84937728ULL;
  const size_t PERCH = 8388608ULL;
  int CH = 8;
  while (CH > 1 && FIXED + (size_t)CH * PERCH > ws_size) CH >>= 1;

  size_t off = 0;
  auto carve = [&](size_t bytes) -> void* {
    void* p = wsb + off;
    off += (bytes + 255) & ~(size_t)255;
    return p;
  };
  unsigned short* xb  = (unsigned short*)carve((size_t)Bb * T * E * 2);
  unsigned short* wqT = (unsigned short*)carve((size_t)H * D * E * 2);
  unsigned short* wkT = (unsigned short*)carve((size_t)H * D * E * 2);
  unsigned short* wvT = (unsigned short*)carve((size_t)H * D * E * 2);
  float*          bos = (float*)carve(E * 4);
  unsigned short* z2  = (unsigned short*)carve((size_t)Bb * T * HD * 2);
  unsigned short* qc  = (unsigned short*)carve((size_t)CH * T * D * 2);
  unsigned short* kc  = (unsigned short*)carve((size_t)CH * T * D * 2);
  unsigned short* vc  = (unsigned short*)carve((size_t)CH * T * D * 2);
  unsigned short* vTc = (unsigned short*)carve((size_t)CH * D * T * 2);
  unsigned short* Sc  = (unsigned short*)carve((size_t)CH * T * T * 2);
  unsigned short* woT = wqT;

  convert_f32_bf16_kernel<<<3072, 256, 0, stream>>>(x, xb, Bb * T * E / 4);
  transpose_conv_kernel<<<dim3(24, 24, 8), tb32, 0, stream>>>(wq, wqT, E, D);
  transpose_conv_kernel<<<dim3(24, 24, 8), tb32, 0, stream>>>(wk, wkT, E, D);
  transpose_conv_kernel<<<dim3(24, 24, 8), tb32, 0, stream>>>(wv, wvT, E, D);
  bosum_kernel<<<3, 256, 0, stream>>>(bo, bos);

  const int nchunks = (Bb * H) / CH;
  for (int c = 0; c < nchunks; ++c) {
    const int z0 = c * CH;
    const int b  = z0 >> 3;
    const int h0 = z0 & 7;
    const unsigned short* xbb = xb + (size_t)b * T * E;

    gemm_bt_kernel<false><<<dim3(6, 8, CH), 256, 0, stream>>>(
        xbb, wqT + (size_t)h0 * DE, qc, bq + (size_t)h0 * D, E, E, E,
        0LL, DE, TD, 0LL, 0, 0LL, 30, D, (long long)D, 1.0f,
        nullptr, nullptr, nullptr);
    gemm_bt_kernel<false><<<dim3(6, 8, CH), 256, 0, stream>>>(
        xbb, wkT + (size_t)h0 * DE, kc, bk + (size_t)h0 * D, E, E, E,
        0LL, DE, TD, 0LL, 0, 0LL, 30, D, (long long)D, 1.0f,
        nullptr, nullptr, nullptr);
    gemm_bt_kernel<false><<<dim3(6, 8, CH), 256, 0, stream>>>(
        xbb, wvT + (size_t)h0 * DE, vc, bv + (size_t)h0 * D, E, E, E,
        0LL, DE, TD, 0LL, 0, 0LL, 30, D, (long long)D, 1.0f,
        nullptr, nullptr, nullptr);

    transpose_bf16_kernel<<<dim3(24, 32, CH), tb32, 0, stream>>>(vc, vTc, T, D);

    gemm_bt_kernel<false><<<dim3(8, 8, CH), 256, 0, stream>>>(
        qc, kc, Sc, nullptr, D, D, D,
        TD, TD, TT, 0LL, 0, 0LL, 30, T, 0LL, SCALE,
        nullptr, nullptr, nullptr);

    softmax_kernel<<<CH * T, 256, 0, stream>>>(Sc);

    gemm_bt_kernel<false><<<dim3(6, 8, CH), 256, 0, stream>>>(
        Sc, vTc, z2 + (size_t)b * T * HD + (size_t)h0 * D, nullptr, T, T, T,
        TT, DT, (long long)D, 0LL, 0, 0LL, 30, HD, 0LL, 1.0f,
        nullptr, nullptr, nullptr);
  }

  transpose_conv_kernel<<<dim3(24, 192, 1), tb32, 0, stream>>>(wo, woT, HD, E);
  gemm_bt_kernel<true><<<dim3(6, 32, 1), 256, 0, stream>>>(
      z2, woT, out, bos, HD, HD, HD,
      0LL, 0LL, 0LL, 0LL, 0, 0LL, 30, E, 0LL, 1.0f,
      nullptr, nullptr, nullptr);
}

// Round 9
// 360.477 us; speedup vs baseline: 1.1419x; 1.1419x over previous
//
#include <hip/hip_runtime.h>
#include <hip/hip_bf16.h>

// ---------------------------------------------------------------------------
// MultiHeadAttention: B=4, T=1024, E=768, D=768, H=8, per-head full-width proj
// All GEMMs: 128x128-tile 4-wave bf16 MFMA (m97 structure) + T2 LDS XOR
// swizzle (0 bank conflicts, verified R6/R7) + T1 XCD swizzle + occupancy
// hint __launch_bounds__(256,4) (VGPR 64, LDS 32KB -> 4-5 blocks/CU possible).
// Fusions: QKV epilogue writes V^T directly; S epilogue = exp + row partial
// sums (softmax denom factored into PV epilogue via invden); out-proj
// split-K=4 + reduce4. 256^2 pipelined kernel removed: 3 attempts all null
// (215us / MfmaUtil 22.7% at nkt=12 shapes vs 128^2's 158us / 33%).
// Fallback (small ws): proven chunked path.
// ---------------------------------------------------------------------------

typedef __bf16 bf16x8 __attribute__((ext_vector_type(8)));
typedef float  f32x4  __attribute__((ext_vector_type(4)));
typedef short  s16x4  __attribute__((ext_vector_type(4)));

#define AS1 __attribute__((address_space(1)))
#define AS3 __attribute__((address_space(3)))

__device__ inline void gload_lds16(const void* g, void* l) {
  // async global->LDS, 16B/lane; LDS dest wave-uniform base + lane*16
  __builtin_amdgcn_global_load_lds((AS1 const void*)g, (AS3 void*)l, 16, 0, 0);
}

__device__ inline unsigned short f2bf(float f) {  // RNE f32 -> bf16 bits
  union { float f; unsigned u; } c; c.f = f;
  unsigned r = c.u + 0x7FFF + ((c.u >> 16) & 1);
  return (unsigned short)(r >> 16);
}
__device__ inline float bf2f(unsigned short u) {
  return __uint_as_float(((unsigned)u) << 16);
}

// XCD-aware bijective remap (T1); valid when total blocks % 8 == 0
__device__ inline void swizzle_bid(int& bx, int& by, int& bz) {
  const int gx = gridDim.x, gy = gridDim.y, gz = gridDim.z;
  const int n = gx * gy * gz;
  if ((n & 7) == 0) {
    int lin = (blockIdx.z * gy + blockIdx.y) * gx + blockIdx.x;
    lin = (lin & 7) * (n >> 3) + (lin >> 3);
    bz = lin / (gx * gy);
    const int rem = lin - bz * gx * gy;
    by = rem / gx;
    bx = rem - by * gx;
  } else {
    bx = blockIdx.x; by = blockIdx.y; bz = blockIdx.z;
  }
}

// ---------------------------------------------------------------------------
// GEMM: C = scale * A * Bt^T (+ bias[z*biasZ + n]); A:[M,lda] bf16, Bt:[N,ldb]
//   zoff  = (z>>zShift)*cZhi + (z & ((1<<zShift)-1))*cZlo
//   rowoff= (m>>rowShift)*cRowHi + (m & ((1<<rowShift)-1))*ldc
//   C[zoff + rowoff + n]
// T2 swizzle: LDS[row][u16B] holds global[row][u ^ (row&7)] (pre-swizzled
// source, linear gload_lds dest); reads XOR the unit back. 0 conflicts (R4-R7).
// Epilogue modes:
//  - vtOut && z>=16  : write C^T into vtOut[b][z-16][n][t] (fused V^T)
//  - rowsumOut       : e=exp(v*scale); write e (bf16) + per-row partial sums
//                      rowsumOut[(z*8+ntile)*1024 + m]   (softmax fused)
//  - rowScale        : v *= rowScale[z*1024+m] before store (PV normalization)
// Grid: (N/128, M/128, Z). 256 threads = 4 waves, each wave 64x64 output.
// __launch_bounds__(256,4): min 4 waves/EU = 4 blocks/CU target (VGPR<=128).
// ---------------------------------------------------------------------------
template<bool OUT_F32>
__global__ __launch_bounds__(256, 4)
void gemm_bt_kernel(const unsigned short* __restrict__ A,
                    const unsigned short* __restrict__ Bt,
                    void* __restrict__ Cout,
                    const float* __restrict__ bias,
                    int K, int lda, int ldb,
                    long long aZ, long long bZ,
                    long long cZhi, long long cZlo, int zShift,
                    long long cRowHi, int rowShift, int ldc,
                    long long biasZ, float scale,
                    unsigned short* __restrict__ vtOut,
                    float* __restrict__ rowsumOut,
                    const float* __restrict__ rowScale)
{
  __shared__ unsigned short As[128 * 64];
  __shared__ unsigned short Bs[128 * 64];

  int ntile, mtile, z;
  swizzle_bid(ntile, mtile, z);

  const int tid  = threadIdx.x;
  const int wave = tid >> 6;
  const int lane = tid & 63;
  const int wm = wave >> 1, wn = wave & 1;

  const unsigned short* Ab = A  + (size_t)z * aZ + (size_t)mtile * 128 * lda;
  const unsigned short* Bb = Bt + (size_t)z * bZ + (size_t)ntile * 128 * ldb;

  const int rlane = lane >> 3;                    // 0..7 row within 8-row group
  const int su    = ((lane & 7) ^ rlane) * 8;     // pre-swizzled source unit

  // swizzled frag-read offsets: u_log = kk*4 + (lane>>4); u_phys = u_log^(lane&7)
  const int rsel  = lane & 15;
  const int usel  = lane & 7;
  const int ubase = lane >> 4;
  const int koff0 = ((ubase) ^ usel) * 8;         // kk=0
  const int koff1 = ((4 | ubase) ^ usel) * 8;     // kk=1

  f32x4 acc[4][4] = {};

  const int nkt = K >> 6;
  for (int kt = 0; kt < nkt; ++kt) {
    const int kbase = kt * 64;
    __syncthreads();
#pragma unroll
    for (int i = 0; i < 4; ++i) {
      const int r = wave * 32 + i * 8;            // wave-uniform base row
      gload_lds16(Ab + (size_t)(r + rlane) * lda + kbase + su, &As[r * 64]);
      gload_lds16(Bb + (size_t)(r + rlane) * ldb + kbase + su, &Bs[r * 64]);
    }
    __syncthreads();
#pragma unroll
    for (int kk = 0; kk < 2; ++kk) {
      const int koff = kk ? koff1 : koff0;
      bf16x8 af[4], bfr[4];
#pragma unroll
      for (int f = 0; f < 4; ++f) {
        af[f]  = *(const bf16x8*)&As[(wm * 64 + f * 16 + rsel) * 64 + koff];
        bfr[f] = *(const bf16x8*)&Bs[(wn * 64 + f * 16 + rsel) * 64 + koff];
      }
#pragma unroll
      for (int fm = 0; fm < 4; ++fm)
#pragma unroll
        for (int fn = 0; fn < 4; ++fn)
          acc[fm][fn] = __builtin_amdgcn_mfma_f32_16x16x32_bf16(af[fm], bfr[fn], acc[fm][fn], 0, 0, 0);
    }
  }

  // C/D frag layout: col = lane&15, row = (lane>>4)*4 + j  [m89]
  if (vtOut && z >= 16) {
    // fused V^T: vT[b][h][d][t], h = z-16; m = b*1024 + t, n = d
    const long long hoff = (long long)(z - 16) * 786432LL;   // D*T
#pragma unroll
    for (int fm = 0; fm < 4; ++fm) {
#pragma unroll
      for (int fn = 0; fn < 4; ++fn) {
        const int n  = ntile * 128 + wn * 64 + fn * 16 + (lane & 15);
        const int m0 = mtile * 128 + wm * 64 + fm * 16 + (lane >> 4) * 4;
        const int b  = m0 >> 10, t0 = m0 & 1023;
        const float bb = bias ? bias[(size_t)z * biasZ + n] : 0.f;
        s16x4 w;
#pragma unroll
        for (int j = 0; j < 4; ++j)
          w[j] = (short)f2bf(acc[fm][fn][j] * scale + bb);
        *(s16x4*)&vtOut[(size_t)b * 6291456 + hoff + (size_t)n * 1024 + t0] = w;
      }
    }
    return;
  }

  const long long zoff = (long long)(z >> zShift) * cZhi
                       + (long long)(z & ((1 << zShift) - 1)) * cZlo;

  if (rowsumOut) {
    // fused exp + per-row partial sums (softmax numerator + denominator parts)
    __syncthreads();                       // all waves done reading As/Bs
    float* redsum = (float*)As;            // [128][2] floats, aliases As
#pragma unroll
    for (int fm = 0; fm < 4; ++fm) {
#pragma unroll
      for (int j = 0; j < 4; ++j) {
        const int m = mtile * 128 + wm * 64 + fm * 16 + (lane >> 4) * 4 + j;
        const long long rowoff = (long long)(m >> rowShift) * cRowHi
                               + (long long)(m & ((1 << rowShift) - 1)) * ldc;
        float part = 0.f;
#pragma unroll
        for (int fn = 0; fn < 4; ++fn) {
          const int n = ntile * 128 + wn * 64 + fn * 16 + (lane & 15);
          const float e = __expf(acc[fm][fn][j] * scale);
          part += e;
          ((unsigned short*)Cout)[zoff + rowoff + n] = f2bf(e);
        }
#pragma unroll
        for (int o = 1; o < 16; o <<= 1) part += __shfl_xor(part, o);
        if ((lane & 15) == 0)
          redsum[(wm * 64 + fm * 16 + (lane >> 4) * 4 + j) * 2 + wn] = part;
      }
    }
    __syncthreads();
    if (tid < 128) {
      const int m = mtile * 128 + tid;
      rowsumOut[((long long)z * 8 + ntile) * 1024 + m] =
          redsum[tid * 2 + 0] + redsum[tid * 2 + 1];
    }
    return;
  }

#pragma unroll
  for (int fm = 0; fm < 4; ++fm) {
#pragma unroll
    for (int j = 0; j < 4; ++j) {
      const int m = mtile * 128 + wm * 64 + fm * 16 + (lane >> 4) * 4 + j;
      const long long rowoff = (long long)(m >> rowShift) * cRowHi
                             + (long long)(m & ((1 << rowShift) - 1)) * ldc;
      const float rsc = rowScale ? rowScale[(size_t)z * 1024 + (m & 1023)] : 1.0f;
#pragma unroll
      for (int fn = 0; fn < 4; ++fn) {
        const int n = ntile * 128 + wn * 64 + fn * 16 + (lane & 15);
        float v = acc[fm][fn][j] * scale;
        if (bias) v += bias[(size_t)z * biasZ + n];
        v *= rsc;
        const long long cidx = zoff + rowoff + n;
        if (OUT_F32) ((float*)Cout)[cidx] = v;
        else ((unsigned short*)Cout)[cidx] = f2bf(v);
      }
    }
  }
}

// merged weight prep: z<24 -> wq/wk/wv head (z&7) -> wqkvT[z]; z>=24 -> woT
__global__ void prep_weights_kernel(const float* __restrict__ wq,
                                    const float* __restrict__ wk,
                                    const float* __restrict__ wv,
                                    const float* __restrict__ wo,
                                    unsigned short* __restrict__ wqkvT,
                                    unsigned short* __restrict__ woT)
{
  __shared__ float tile[32][33];
  const int z = blockIdx.z;
  const float* in;
  unsigned short* outp;
  int outLD;
  if (z < 24) {
    const float* base = (z < 8) ? wq : (z < 16) ? wk : wv;
    in   = base + (size_t)(z & 7) * 589824;
    outp = wqkvT + (size_t)z * 589824;
    outLD = 768;
  } else {
    in   = wo + (size_t)(z - 24) * 589824;
    outp = woT + (size_t)(z - 24) * 768;
    outLD = 6144;
  }
  const int c0 = blockIdx.x * 32, r0 = blockIdx.y * 32;
  const int tx = threadIdx.x, ty = threadIdx.y;
#pragma unroll
  for (int i = ty; i < 32; i += 8)
    tile[i][tx] = in[(size_t)(r0 + i) * 768 + c0 + tx];
  __syncthreads();
#pragma unroll
  for (int i = ty; i < 32; i += 8)
    outp[(size_t)(c0 + i) * outLD + r0 + tx] = f2bf(tile[tx][i]);
}

// fp32 [Z][R][C] -> bf16 [Z][C][R] (fallback path)
__global__ void transpose_conv_kernel(const float* __restrict__ in,
                                      unsigned short* __restrict__ out,
                                      int R, int C)
{
  __shared__ float tile[32][33];
  const size_t zo = (size_t)blockIdx.z * R * C;
  const int c0 = blockIdx.x * 32, r0 = blockIdx.y * 32;
  const int tx = threadIdx.x, ty = threadIdx.y;
#pragma unroll
  for (int i = ty; i < 32; i += 8)
    tile[i][tx] = in[zo + (size_t)(r0 + i) * C + c0 + tx];
  __syncthreads();
#pragma unroll
  for (int i = ty; i < 32; i += 8)
    out[zo + (size_t)(c0 + i) * R + r0 + tx] = f2bf(tile[tx][i]);
}

// bf16 [Z][R][C] -> bf16 [Z][C][R] (fallback path)
__global__ void transpose_bf16_kernel(const unsigned short* __restrict__ in,
                                      unsigned short* __restrict__ out,
                                      int R, int C)
{
  __shared__ unsigned short tile[32][33];
  const size_t zo = (size_t)blockIdx.z * R * C;
  const int c0 = blockIdx.x * 32, r0 = blockIdx.y * 32;
  const int tx = threadIdx.x, ty = threadIdx.y;
#pragma unroll
  for (int i = ty; i < 32; i += 8)
    tile[i][tx] = in[zo + (size_t)(r0 + i) * C + c0 + tx];
  __syncthreads();
#pragma unroll
  for (int i = ty; i < 32; i += 8)
    out[zo + (size_t)(c0 + i) * R + r0 + tx] = tile[tx][i];
}

__global__ void convert_f32_bf16_kernel(const float* __restrict__ in,
                                        unsigned short* __restrict__ out, int n4)
{
  const int i = blockIdx.x * blockDim.x + threadIdx.x;
  if (i < n4) {
    const float4 f = ((const float4*)in)[i];
    s16x4 o;
    o[0] = (short)f2bf(f.x); o[1] = (short)f2bf(f.y);
    o[2] = (short)f2bf(f.z); o[3] = (short)f2bf(f.w);
    ((s16x4*)out)[i] = o;
  }
}

__global__ void bosum_kernel(const float* __restrict__ bo, float* __restrict__ bos)
{
  const int e = blockIdx.x * blockDim.x + threadIdx.x;
  if (e < 768) {
    float s = 0.f;
#pragma unroll
    for (int h = 0; h < 8; ++h) s += bo[h * 768 + e];
    bos[e] = s;
  }
}

__global__ void bconcat_kernel(const float* __restrict__ bq,
                               const float* __restrict__ bk,
                               const float* __restrict__ bv,
                               float* __restrict__ bqkv)
{
  const int i = blockIdx.x * blockDim.x + threadIdx.x;
  if (i < 24 * 768) {
    const int z = i / 768, d = i - z * 768;
    const float* src = (z < 8) ? bq : (z < 16) ? bk : bv;
    bqkv[i] = src[(z & 7) * 768 + d];
  }
}

// invden[z*1024+t] = 1 / sum_{nt<NT} rowsum[(z*NT+nt)*1024 + t]
__global__ void invden_kernel(const float* __restrict__ rowsum,
                              float* __restrict__ invden, int NT)
{
  const int i = blockIdx.x * blockDim.x + threadIdx.x;
  if (i < 32 * 1024) {
    const int z = i >> 10, t = i & 1023;
    const float* p = rowsum + (size_t)z * NT * 1024 + t;
    float s = 0.f;
    for (int nt = 0; nt < NT; ++nt) s += p[nt * 1024];
    invden[i] = 1.0f / s;
  }
}

__global__ void reduce4_kernel(const float* __restrict__ partials,
                               const float* __restrict__ bos,
                               float* __restrict__ out, int n4)
{
  const int i = blockIdx.x * blockDim.x + threadIdx.x;
  if (i < n4) {
    const long long stride4 = 4096LL * 768 / 4;
    float4 a = ((const float4*)partials)[i];
    float4 b = ((const float4*)partials)[i + stride4];
    float4 c = ((const float4*)partials)[i + 2 * stride4];
    float4 d = ((const float4*)partials)[i + 3 * stride4];
    const int col = (i * 4) % 768;
    const float4 b4 = *(const float4*)&bos[col];
    float4 r;
    r.x = a.x + b.x + c.x + d.x + b4.x;
    r.y = a.y + b.y + c.y + d.y + b4.y;
    r.z = a.z + b.z + c.z + d.z + b4.z;
    r.w = a.w + b.w + c.w + d.w + b4.w;
    ((float4*)out)[i] = r;
  }
}

// in-place row softmax (fallback path only)
__global__ __launch_bounds__(256)
void softmax_kernel(unsigned short* __restrict__ S)
{
  const size_t row = blockIdx.x;
  unsigned short* p = S + row * 1024;
  const int t = threadIdx.x;

  s16x4 raw = *((const s16x4*)p + t);
  float v[4];
#pragma unroll
  for (int j = 0; j < 4; ++j) v[j] = bf2f((unsigned short)raw[j]);

  float mx = fmaxf(fmaxf(v[0], v[1]), fmaxf(v[2], v[3]));
#pragma unroll
  for (int o = 1; o < 64; o <<= 1) mx = fmaxf(mx, __shfl_xor(mx, o));

  __shared__ float red[8];
  if ((t & 63) == 0) red[t >> 6] = mx;
  __syncthreads();
  mx = fmaxf(fmaxf(red[0], red[1]), fmaxf(red[2], red[3]));

  float e[4], s = 0.f;
#pragma unroll
  for (int j = 0; j < 4; ++j) { e[j] = __expf(v[j] - mx); s += e[j]; }
#pragma unroll
  for (int o = 1; o < 64; o <<= 1) s += __shfl_xor(s, o);
  if ((t & 63) == 0) red[4 + (t >> 6)] = s;
  __syncthreads();
  s = red[4] + red[5] + red[6] + red[7];
  const float inv = 1.0f / s;

  s16x4 outv;
#pragma unroll
  for (int j = 0; j < 4; ++j) outv[j] = (short)f2bf(e[j] * inv);
  *((s16x4*)p + t) = outv;
}

// ---------------------------------------------------------------------------
extern "C" void kernel_launch(void* const* d_in, const int* in_sizes, int n_in,
                              void* d_out, int out_size, void* d_ws, size_t ws_size,
                              hipStream_t stream)
{
  (void)in_sizes; (void)n_in; (void)out_size;
  constexpr int Bb = 4, T = 1024, E = 768, D = 768, H = 8;
  constexpr int HD = H * D;
  constexpr long long TD = (long long)T * D;
  constexpr long long TT = (long long)T * T;
  constexpr long long DE = (long long)D * E;
  constexpr long long DT = (long long)D * T;
  constexpr long long BHTD = (long long)Bb * H * T * D;
  constexpr long long HTD = (long long)H * TD;
  constexpr float SCALE = 0.03608439182435161f;   // 1/sqrt(E)

  const float* x  = (const float*)d_in[0];
  const float* wq = (const float*)d_in[1];
  const float* bq = (const float*)d_in[2];
  const float* wk = (const float*)d_in[3];
  const float* bk = (const float*)d_in[4];
  const float* wv = (const float*)d_in[5];
  const float* bv = (const float*)d_in[6];
  const float* wo = (const float*)d_in[7];
  const float* bo = (const float*)d_in[8];
  float* out = (float*)d_out;

  unsigned char* wsb = (unsigned char*)d_ws;
  const dim3 tb32(32, 8);

  // ---- ALL32 tier peak footprint: 245,443,584 B ----
  if (ws_size >= 245443584ULL + 4096ULL) {
    unsigned short* woT   = (unsigned short*)(wsb + 0);
    float*          bos   = (float*)(wsb + 9437184);
    float*          bqkv  = (float*)(wsb + 9440256);
    unsigned short* vT    = (unsigned short*)(wsb + 9513984);
    unsigned short* qkv   = (unsigned short*)(wsb + 59845632);
    unsigned short* q     = qkv;
    unsigned short* k     = qkv + BHTD;
    unsigned short* xb    = (unsigned short*)(wsb + 210840576);
    unsigned short* wqkvT = (unsigned short*)(wsb + 217132032);
    unsigned short* S     = qkv + 2 * BHTD;   // v region; overlays xb+wqkvT head
    float*          part  = (float*)k;        // 4x12.6MB fits dead k exactly
    unsigned short* z2    = q;                // overlays dead q
    float*          rowsum = (float*)(wsb + 227617792);
    float*          invden = (float*)(wsb + 228666368);

    // --- prep ---
    convert_f32_bf16_kernel<<<3072, 256, 0, stream>>>(x, xb, Bb * T * E / 4);
    prep_weights_kernel<<<dim3(24, 24, 32), tb32, 0, stream>>>(
        wq, wk, wv, wo, wqkvT, woT);
    bosum_kernel<<<3, 256, 0, stream>>>(bo, bos);
    bconcat_kernel<<<72, 256, 0, stream>>>(bq, bk, bv, bqkv);

    // --- fused QKV: z = proj*8 + h; z>=16 (V) writes vT[b][h][d][t] directly
    gemm_bt_kernel<false><<<dim3(6, 32, 24), 256, 0, stream>>>(
        xb, wqkvT, qkv, bqkv, E, E, E,
        0LL, DE, BHTD, TD, 3, HTD, 10, D, 768LL, 1.0f, vT, nullptr, nullptr);

    // --- E = exp(scale * q k^T) + row partial sums (fused softmax part 1) ---
    gemm_bt_kernel<false><<<dim3(8, 8, 32), 256, 0, stream>>>(
        q, k, S, nullptr, D, D, D,
        TD, TD, TT, 0LL, 0, 0LL, 30, T, 0LL, SCALE, nullptr, rowsum, nullptr);

    // --- invden[z][t] = 1/sum (fused softmax part 2) ---
    invden_kernel<<<128, 256, 0, stream>>>(rowsum, invden, 8);

    // --- z2[b,t,h*D+n] = (E v) * invden : z = b*8+h ---
    gemm_bt_kernel<false><<<dim3(6, 8, 32), 256, 0, stream>>>(
        S, vT, z2, nullptr, T, T, T,
        TT, DT, (long long)T * HD, (long long)D, 3, 0LL, 30, HD, 0LL, 1.0f,
        nullptr, nullptr, invden);

    // --- out-proj split-K=4: partials[kz][4096][768] fp32 ---
    gemm_bt_kernel<true><<<dim3(6, 32, 4), 256, 0, stream>>>(
        z2, woT, part, nullptr, 1536, HD, HD,
        1536LL, 1536LL, 3145728LL, 0LL, 0, 0LL, 30, E, 0LL, 1.0f,
        nullptr, nullptr, nullptr);
    reduce4_kernel<<<3072, 256, 0, stream>>>(part, bos, out, 4096 * 768 / 4);
    return;
  }

  // ---------------- fallback: proven chunked path ----------------
  const size_t FIXED = 84937728ULL;
  const size_t PERCH = 8388608ULL;
  int CH = 8;
  while (CH > 1 && FIXED + (size_t)CH * PERCH > ws_size) CH >>= 1;

  size_t off = 0;
  auto carve = [&](size_t bytes) -> void* {
    void* p = wsb + off;
    off += (bytes + 255) & ~(size_t)255;
    return p;
  };
  unsigned short* xb  = (unsigned short*)carve((size_t)Bb * T * E * 2);
  unsigned short* wqT = (unsigned short*)carve((size_t)H * D * E * 2);
  unsigned short* wkT = (unsigned short*)carve((size_t)H * D * E * 2);
  unsigned short* wvT = (unsigned short*)carve((size_t)H * D * E * 2);
  float*          bos = (float*)carve(E * 4);
  unsigned short* z2  = (unsigned short*)carve((size_t)Bb * T * HD * 2);
  unsigned short* qc  = (unsigned short*)carve((size_t)CH * T * D * 2);
  unsigned short* kc  = (unsigned short*)carve((size_t)CH * T * D * 2);
  unsigned short* vc  = (unsigned short*)carve((size_t)CH * T * D * 2);
  unsigned short* vTc = (unsigned short*)carve((size_t)CH * D * T * 2);
  unsigned short* Sc  = (unsigned short*)carve((size_t)CH * T * T * 2);
  unsigned short* woT = wqT;

  convert_f32_bf16_kernel<<<3072, 256, 0, stream>>>(x, xb, Bb * T * E / 4);
  transpose_conv_kernel<<<dim3(24, 24, 8), tb32, 0, stream>>>(wq, wqT, E, D);
  transpose_conv_kernel<<<dim3(24, 24, 8), tb32, 0, stream>>>(wk, wkT, E, D);
  transpose_conv_kernel<<<dim3(24, 24, 8), tb32, 0, stream>>>(wv, wvT, E, D);
  bosum_kernel<<<3, 256, 0, stream>>>(bo, bos);

  const int nchunks = (Bb * H) / CH;
  for (int c = 0; c < nchunks; ++c) {
    const int z0 = c * CH;
    const int b  = z0 >> 3;
    const int h0 = z0 & 7;
    const unsigned short* xbb = xb + (size_t)b * T * E;

    gemm_bt_kernel<false><<<dim3(6, 8, CH), 256, 0, stream>>>(
        xbb, wqT + (size_t)h0 * DE, qc, bq + (size_t)h0 * D, E, E, E,
        0LL, DE, TD, 0LL, 0, 0LL, 30, D, (long long)D, 1.0f,
        nullptr, nullptr, nullptr);
    gemm_bt_kernel<false><<<dim3(6, 8, CH), 256, 0, stream>>>(
        xbb, wkT + (size_t)h0 * DE, kc, bk + (size_t)h0 * D, E, E, E,
        0LL, DE, TD, 0LL, 0, 0LL, 30, D, (long long)D, 1.0f,
        nullptr, nullptr, nullptr);
    gemm_bt_kernel<false><<<dim3(6, 8, CH), 256, 0, stream>>>(
        xbb, wvT + (size_t)h0 * DE, vc, bv + (size_t)h0 * D, E, E, E,
        0LL, DE, TD, 0LL, 0, 0LL, 30, D, (long long)D, 1.0f,
        nullptr, nullptr, nullptr);

    transpose_bf16_kernel<<<dim3(24, 32, CH), tb32, 0, stream>>>(vc, vTc, T, D);

    gemm_bt_kernel<false><<<dim3(8, 8, CH), 256, 0, stream>>>(
        qc, kc, Sc, nullptr, D, D, D,
        TD, TD, TT, 0LL, 0, 0LL, 30, T, 0LL, SCALE,
        nullptr, nullptr, nullptr);

    softmax_kernel<<<CH * T, 256, 0, stream>>>(Sc);

    gemm_bt_kernel<false><<<dim3(6, 8, CH), 256, 0, stream>>>(
        Sc, vTc, z2 + (size_t)b * T * HD + (size_t)h0 * D, nullptr, T, T, T,
        TT, DT, (long long)D, 0LL, 0, 0LL, 30, HD, 0LL, 1.0f,
        nullptr, nullptr, nullptr);
  }

  transpose_conv_kernel<<<dim3(24, 192, 1), tb32, 0, stream>>>(wo, woT, HD, E);
  gemm_bt_kernel<true><<<dim3(6, 32, 1), 256, 0, stream>>>(
      z2, woT, out, bos, HD, HD, HD,
      0LL, 0LL, 0LL, 0LL, 0, 0LL, 30, E, 0LL, 1.0f,
      nullptr, nullptr, nullptr);
}